// Round 7
// baseline (316.740 us; speedup 1.0000x reference)
//
#include <hip/hip_runtime.h>
#include <hip/hip_bf16.h>
#include <math.h>

#define T_TOK 4096
#define DIM   1024
#define NEXP  8
#define DHID  4096
#define NDOUT 1024
#define BM    128
#define MAXTILES 40   // sum ceil(c_e/128) <= 32+7

typedef short bf16x8 __attribute__((ext_vector_type(8)));
typedef float f32x4 __attribute__((ext_vector_type(4)));

__device__ __forceinline__ unsigned short f2bf(float f) {
  unsigned u = __float_as_uint(f);
  u += 0x7fffu + ((u >> 16) & 1u);        // RNE
  return (unsigned short)(u >> 16);
}
__device__ __forceinline__ unsigned pack2bf(float a, float b) {
  return (unsigned)f2bf(a) | ((unsigned)f2bf(b) << 16);
}
__device__ __forceinline__ void gl_lds16(const void* g, void* l) {
  __builtin_amdgcn_global_load_lds(
      (const __attribute__((address_space(1))) void*)g,
      (__attribute__((address_space(3))) void*)l, 16, 0, 0);
}
#define SBAR()  __builtin_amdgcn_s_barrier()
#define SCHED() __builtin_amdgcn_sched_barrier(0)

// -------- gate + x->bf16 conversion fused (1 wave/token, fp64 accum) --------
__global__ __launch_bounds__(256)
void gate_kernel(const float* __restrict__ x, const float* __restrict__ Wg,
                 const float* __restrict__ bg, int* __restrict__ sel,
                 unsigned short* __restrict__ xbf) {
  int lane = threadIdx.x & 63;
  int wid  = threadIdx.x >> 6;
  int t = blockIdx.x * 4 + wid;
  if (t >= T_TOK) return;
  const float* xr = x + (size_t)t * DIM;
  unsigned short* xbr = xbf + (size_t)t * DIM;
  double acc[NEXP];
#pragma unroll
  for (int e = 0; e < NEXP; e++) acc[e] = 0.0;
#pragma unroll
  for (int j = 0; j < 4; j++) {
    int d0 = j * 256 + lane * 4;
    float4 v = *(const float4*)(xr + d0);
    uint2 p; p.x = pack2bf(v.x, v.y); p.y = pack2bf(v.z, v.w);
    *(uint2*)(xbr + d0) = p;
    float xs[4] = {v.x, v.y, v.z, v.w};
#pragma unroll
    for (int i = 0; i < 4; i++) {
      const float4* wr = reinterpret_cast<const float4*>(Wg + (size_t)(d0 + i) * NEXP);
      float4 w0 = wr[0], w1 = wr[1];
      double xv = (double)xs[i];
      acc[0] += xv * (double)w0.x;
      acc[1] += xv * (double)w0.y;
      acc[2] += xv * (double)w0.z;
      acc[3] += xv * (double)w0.w;
      acc[4] += xv * (double)w1.x;
      acc[5] += xv * (double)w1.y;
      acc[6] += xv * (double)w1.z;
      acc[7] += xv * (double)w1.w;
    }
  }
#pragma unroll
  for (int off = 32; off >= 1; off >>= 1) {
#pragma unroll
    for (int e = 0; e < NEXP; e++) acc[e] += __shfl_down(acc[e], off);
  }
  if (lane == 0) {
    double best = acc[0] + (double)bg[0];
    int bi = 0;
#pragma unroll
    for (int e = 1; e < NEXP; e++) {
      double v = acc[e] + (double)bg[e];
      if (v > best) { best = v; bi = e; }   // strict > : first max wins
    }
    sel[t] = bi;
  }
}

// ---------------- routing bookkeeping ----------------
__global__ void zero_kernel(int* __restrict__ counts) {
  if (threadIdx.x < NEXP) counts[threadIdx.x] = 0;
}

__global__ void hist_kernel(const int* __restrict__ sel, int* __restrict__ counts) {
  __shared__ int lc[NEXP];
  if (threadIdx.x < NEXP) lc[threadIdx.x] = 0;
  __syncthreads();
  int t = blockIdx.x * 256 + threadIdx.x;
  atomicAdd(&lc[sel[t]], 1);
  __syncthreads();
  if (threadIdx.x < NEXP) atomicAdd(&counts[threadIdx.x], lc[threadIdx.x]);
}

__global__ void plan_kernel(const int* __restrict__ counts, int* __restrict__ base,
                            int* __restrict__ cursor, int* __restrict__ tileExpert,
                            int* __restrict__ tilePos, int* __restrict__ tileRows,
                            int* __restrict__ ntiles) {
  if (threadIdx.x == 0) {
    int acc = 0, nt = 0;
    for (int e = 0; e < NEXP; e++) {
      base[e] = acc; cursor[e] = acc;
      int c = counts[e];
      for (int j = 0; j < c; j += BM) {
        tileExpert[nt] = e;
        tilePos[nt]    = acc + j;
        int rem = c - j;
        tileRows[nt]   = rem < BM ? rem : BM;
        nt++;
      }
      acc += c;
    }
    *ntiles = nt;
  }
}

__global__ void scatter_kernel(const int* __restrict__ sel, int* __restrict__ cursor,
                               int* __restrict__ list) {
  __shared__ int lcnt[NEXP];
  __shared__ int lbase[NEXP];
  int tid = threadIdx.x;
  if (tid < NEXP) lcnt[tid] = 0;
  __syncthreads();
  int t = blockIdx.x * 256 + tid;
  int e = sel[t];
  int lpos = atomicAdd(&lcnt[e], 1);
  __syncthreads();
  if (tid < NEXP) lbase[tid] = atomicAdd(&cursor[tid], lcnt[tid]);
  __syncthreads();
  list[lbase[e] + lpos] = t;
}

// [E][K][N] fp32 -> tiled swizzled bf16: [E][N/128][K/64] 16KB tiles whose byte
// order equals the GEMM's LDS image: tile[r*128 + (2k ^ ((r&7)<<4))] = elem(n=r, k)
__global__ __launch_bounds__(256)
void transpose_tile_kernel(const float* __restrict__ in, unsigned short* __restrict__ out,
                           int K, int N) {
  int nb = blockIdx.x, kb = blockIdx.y, e = blockIdx.z;
  const float* inp = in + (size_t)e * K * N;
  __shared__ unsigned short lds[128][72];
  int tx = threadIdx.x;
  int kloc = tx >> 5;            // 0..7
  int n4   = (tx & 31) << 2;     // 0..124
#pragma unroll
  for (int p = 0; p < 8; p++) {
    int k = p * 8 + kloc;
    float4 v = *(const float4*)(inp + (size_t)(kb * 64 + k) * N + nb * 128 + n4);
    lds[n4 + 0][k] = f2bf(v.x);
    lds[n4 + 1][k] = f2bf(v.y);
    lds[n4 + 2][k] = f2bf(v.z);
    lds[n4 + 3][k] = f2bf(v.w);
  }
  __syncthreads();
  char* tile = (char*)(out + (((size_t)e * gridDim.x + nb) * gridDim.y + kb) * 8192);
  int r  = tx >> 1;
  int kc0 = (tx & 1) * 32;
#pragma unroll
  for (int c = 0; c < 4; c++) {
    int kc = kc0 + c * 8;
    uint4 v = *(const uint4*)&lds[r][kc];
    *(uint4*)(tile + r * 128 + ((2 * kc) ^ ((r & 7) << 4))) = v;
  }
}

// ===== double-buffered counted-vmcnt 128x128 grouped GEMMs =====
// 256 thr = 4 waves (2x2), per-wave 64x64 out, LDS 2x32KB. Per K-iter:
// STAGE(buf^1, kt+1) -> vmcnt(8) (retires tile kt's 8 loads, keeps 8 in
// flight) -> s_barrier (publish) -> compute(buf) -> s_barrier (WAR guard).
// Never vmcnt(0) inside the loop.

__global__ __launch_bounds__(256)
void gemm1_kernel(const unsigned short* __restrict__ xbf, const unsigned short* __restrict__ W1T,
                  const float* __restrict__ b1, const int* __restrict__ list,
                  const int* __restrict__ tileExpert, const int* __restrict__ tilePos,
                  const int* __restrict__ tileRows, const int* __restrict__ ntiles,
                  unsigned short* __restrict__ HcT) {
  int tIdx = blockIdx.y;
  if (tIdx >= *ntiles) return;
  int e = tileExpert[tIdx], posBase = tilePos[tIdx], rows = tileRows[tIdx];
  int nb = blockIdx.x;

  __shared__ __align__(1024) char As[2][16384];
  __shared__ __align__(1024) char Bs[2][16384];

  const int tx = threadIdx.x, lane = tx & 63, w = tx >> 6;
  const int wm = w >> 1, wn = w & 1;
  const int rsub = lane >> 3;
  const int px = ((lane & 7) ^ rsub) << 4;   // pre-swizzled source for row-major A

  const char* aS[4];
#pragma unroll
  for (int j = 0; j < 4; j++) {
    int r = w * 32 + j * 8 + rsub;
    int tok = list[posBase + (r < rows ? r : rows - 1)];
    aS[j] = (const char*)xbf + (size_t)tok * (DIM * 2) + px;
  }
  const char* bTile = (const char*)W1T + (((size_t)e * (DHID / 128) + nb) * (DIM / 64)) * 16384
                      + w * 4096 + lane * 16;

  auto STAGE = [&](int buf, int kt) {
#pragma unroll
    for (int j = 0; j < 4; j++) {
      gl_lds16(aS[j] + kt * 128, &As[buf][(w * 32 + j * 8) * 128]);
      gl_lds16(bTile + kt * 16384 + j * 1024, &Bs[buf][w * 4096 + j * 1024]);
    }
  };

  f32x4 acc[4][4];
#pragma unroll
  for (int mf = 0; mf < 4; mf++)
#pragma unroll
    for (int nf = 0; nf < 4; nf++)
      acc[mf][nf] = f32x4{0.f, 0.f, 0.f, 0.f};

  auto COMPUTE = [&](int buf) {
#pragma unroll
    for (int ks = 0; ks < 2; ks++) {
      int koff = (ks * 64 + (lane >> 4) * 16) ^ ((lane & 7) << 4);
      bf16x8 aF[4], bF[4];
#pragma unroll
      for (int mf = 0; mf < 4; mf++)
        aF[mf] = *(const bf16x8*)&As[buf][(wm * 64 + mf * 16 + (lane & 15)) * 128 + koff];
#pragma unroll
      for (int nf = 0; nf < 4; nf++)
        bF[nf] = *(const bf16x8*)&Bs[buf][(wn * 64 + nf * 16 + (lane & 15)) * 128 + koff];
#pragma unroll
      for (int mf = 0; mf < 4; mf++)
#pragma unroll
        for (int nf = 0; nf < 4; nf++)
          acc[mf][nf] = __builtin_amdgcn_mfma_f32_16x16x32_bf16(aF[mf], bF[nf], acc[mf][nf], 0, 0, 0);
    }
  };

  const int NT = DIM / 64;   // 16
  STAGE(0, 0);
  for (int kt = 0; kt < NT; kt++) {
    int buf = kt & 1;
    if (kt + 1 < NT) {
      STAGE(buf ^ 1, kt + 1);
      asm volatile("s_waitcnt vmcnt(8)" ::: "memory");
    } else {
      asm volatile("s_waitcnt vmcnt(0)" ::: "memory");
    }
    SCHED(); SBAR(); SCHED();
    COMPUTE(buf);
    SCHED(); SBAR(); SCHED();
  }

  // Epilogue: bias + gelu, write Hc as tiled swizzled image for gemm2's A.
  const float* b1e = b1 + (size_t)e * DHID;
  char* hBase = (char*)(HcT + (size_t)tIdx * (DHID / 64) * 8192);
#pragma unroll
  for (int nf = 0; nf < 4; nf++) {
    int col = nb * 128 + wn * 64 + nf * 16 + (lane & 15);
    int kt2 = col >> 6;
    int colk2 = (col & 63) * 2;
    float bias = b1e[col];
    char* tile = hBase + (size_t)kt2 * 16384;
#pragma unroll
    for (int mf = 0; mf < 4; mf++) {
#pragma unroll
      for (int j = 0; j < 4; j++) {
        int r = wm * 64 + mf * 16 + ((lane >> 4) << 2) + j;
        float h = acc[mf][nf][j] + bias;
        float g = 0.5f * h * (1.0f + erff(h * 0.70710678118654752f));
        *(unsigned short*)(tile + r * 128 + (colk2 ^ ((r & 7) << 4))) = f2bf(g);
      }
    }
  }
}

// GEMM2 split-K=2 (z in {0,1}, 32 K-tiles each): fp32 partials, bias in z=0.
__global__ __launch_bounds__(256)
void gemm2_kernel(const unsigned short* __restrict__ HcT, const unsigned short* __restrict__ W2T,
                  const float* __restrict__ b2, const int* __restrict__ tileExpert,
                  const int* __restrict__ tilePos, const int* __restrict__ tileRows,
                  const int* __restrict__ ntiles, float* __restrict__ Ppart) {
  int tIdx = blockIdx.y;
  if (tIdx >= *ntiles) return;
  int e = tileExpert[tIdx], posBase = tilePos[tIdx], rows = tileRows[tIdx];
  int nb = blockIdx.x;
  int zs = blockIdx.z;

  __shared__ __align__(1024) char As[2][16384];
  __shared__ __align__(1024) char Bs[2][16384];

  const int tx = threadIdx.x, lane = tx & 63, w = tx >> 6;
  const int wm = w >> 1, wn = w & 1;

  const char* aTile = (const char*)HcT + (size_t)tIdx * (DHID / 64) * 16384
                      + (size_t)zs * 32 * 16384 + w * 4096 + lane * 16;
  const char* bTile = (const char*)W2T + (((size_t)e * (NDOUT / 128) + nb) * (DHID / 64)) * 16384
                      + (size_t)zs * 32 * 16384 + w * 4096 + lane * 16;

  auto STAGE = [&](int buf, int kt) {
#pragma unroll
    for (int j = 0; j < 4; j++) {
      gl_lds16(aTile + kt * 16384 + j * 1024, &As[buf][w * 4096 + j * 1024]);
      gl_lds16(bTile + kt * 16384 + j * 1024, &Bs[buf][w * 4096 + j * 1024]);
    }
  };

  f32x4 acc[4][4];
#pragma unroll
  for (int mf = 0; mf < 4; mf++)
#pragma unroll
    for (int nf = 0; nf < 4; nf++)
      acc[mf][nf] = f32x4{0.f, 0.f, 0.f, 0.f};

  auto COMPUTE = [&](int buf) {
#pragma unroll
    for (int ks = 0; ks < 2; ks++) {
      int koff = (ks * 64 + (lane >> 4) * 16) ^ ((lane & 7) << 4);
      bf16x8 aF[4], bF[4];
#pragma unroll
      for (int mf = 0; mf < 4; mf++)
        aF[mf] = *(const bf16x8*)&As[buf][(wm * 64 + mf * 16 + (lane & 15)) * 128 + koff];
#pragma unroll
      for (int nf = 0; nf < 4; nf++)
        bF[nf] = *(const bf16x8*)&Bs[buf][(wn * 64 + nf * 16 + (lane & 15)) * 128 + koff];
#pragma unroll
      for (int mf = 0; mf < 4; mf++)
#pragma unroll
        for (int nf = 0; nf < 4; nf++)
          acc[mf][nf] = __builtin_amdgcn_mfma_f32_16x16x32_bf16(aF[mf], bF[nf], acc[mf][nf], 0, 0, 0);
    }
  };

  const int NT = 32;
  STAGE(0, 0);
  for (int kt = 0; kt < NT; kt++) {
    int buf = kt & 1;
    if (kt + 1 < NT) {
      STAGE(buf ^ 1, kt + 1);
      asm volatile("s_waitcnt vmcnt(8)" ::: "memory");
    } else {
      asm volatile("s_waitcnt vmcnt(0)" ::: "memory");
    }
    SCHED(); SBAR(); SCHED();
    COMPUTE(buf);
    SCHED(); SBAR(); SCHED();
  }

  const float* b2e = b2 + (size_t)e * NDOUT;
  float* P = Ppart + (size_t)zs * T_TOK * NDOUT;
#pragma unroll
  for (int nf = 0; nf < 4; nf++) {
    int col = nb * 128 + wn * 64 + nf * 16 + (lane & 15);
    float bias = (zs == 0) ? b2e[col] : 0.f;
#pragma unroll
    for (int mf = 0; mf < 4; mf++)
#pragma unroll
      for (int j = 0; j < 4; j++) {
        int rloc = wm * 64 + mf * 16 + ((lane >> 4) << 2) + j;
        if (rloc < rows)
          P[(size_t)(posBase + rloc) * NDOUT + col] = acc[mf][nf][j] + bias;
      }
  }
}

// out[list[pos]] = P0[pos] + P1[pos]   (bias already in P0)
__global__ __launch_bounds__(256)
void reduce_kernel(const float* __restrict__ Ppart, const int* __restrict__ list,
                   float* __restrict__ out) {
  int pos = blockIdx.x;
  int tok = list[pos];
  int c = threadIdx.x * 4;
  float4 a = *(const float4*)(Ppart + (size_t)pos * NDOUT + c);
  float4 b = *(const float4*)(Ppart + (size_t)T_TOK * NDOUT + (size_t)pos * NDOUT + c);
  float4 o; o.x = a.x + b.x; o.y = a.y + b.y; o.z = a.z + b.z; o.w = a.w + b.w;
  *(float4*)(out + (size_t)tok * NDOUT + c) = o;
}

// ---------------- launch ----------------
extern "C" void kernel_launch(void* const* d_in, const int* in_sizes, int n_in,
                              void* d_out, int out_size, void* d_ws, size_t ws_size,
                              hipStream_t stream) {
  const float* x  = (const float*)d_in[0];
  const float* Wg = (const float*)d_in[1];
  const float* bg = (const float*)d_in[2];
  const float* W1 = (const float*)d_in[3];
  const float* b1 = (const float*)d_in[4];
  const float* W2 = (const float*)d_in[5];
  const float* b2 = (const float*)d_in[6];
  float* out = (float*)d_out;

  char* ws = (char*)d_ws;
  int* sel        = (int*)(ws);
  int* counts     = (int*)(ws + 16384);
  int* base       = (int*)(ws + 16448);
  int* cursor     = (int*)(ws + 16512);
  int* ntiles     = (int*)(ws + 16576);
  int* tileExpert = (int*)(ws + 16640);
  int* tilePos    = (int*)(ws + 16832);
  int* tileRows   = (int*)(ws + 17024);
  int* list       = (int*)(ws + 17408);

  unsigned short* xbf = (unsigned short*)(ws + (1ull << 20));    // 8 MB
  unsigned short* HcT = (unsigned short*)(ws + (10ull << 20));   // 40 MB tiled Hc
  unsigned short* W1T = (unsigned short*)(ws + (52ull << 20));   // 64 MB tiled
  unsigned short* W2T = (unsigned short*)(ws + (116ull << 20));  // 64 MB tiled
  float* Ppart        = (float*)(ws + (52ull << 20));            // reuse W1T region (2x16.8 MB)

  gate_kernel<<<T_TOK / 4, 256, 0, stream>>>(x, Wg, bg, sel, xbf);
  zero_kernel<<<1, 64, 0, stream>>>(counts);
  hist_kernel<<<T_TOK / 256, 256, 0, stream>>>(sel, counts);
  plan_kernel<<<1, 64, 0, stream>>>(counts, base, cursor, tileExpert, tilePos, tileRows, ntiles);
  scatter_kernel<<<T_TOK / 256, 256, 0, stream>>>(sel, cursor, list);

  transpose_tile_kernel<<<dim3(DHID / 128, DIM / 64, NEXP), 256, 0, stream>>>(W1, W1T, DIM, DHID);
  transpose_tile_kernel<<<dim3(NDOUT / 128, DHID / 64, NEXP), 256, 0, stream>>>(W2, W2T, DHID, NDOUT);

  gemm1_kernel<<<dim3(DHID / 128, MAXTILES), 256, 0, stream>>>(
      xbf, W1T, b1, list, tileExpert, tilePos, tileRows, ntiles, HcT);
  gemm2_kernel<<<dim3(NDOUT / 128, MAXTILES, 2), 256, 0, stream>>>(
      HcT, W2T, b2, tileExpert, tilePos, tileRows, ntiles, Ppart);
  reduce_kernel<<<T_TOK, 256, 0, stream>>>(Ppart, list, out);
}

// Round 8
// 297.408 us; speedup vs baseline: 1.0650x; 1.0650x over previous
//
#include <hip/hip_runtime.h>
#include <hip/hip_bf16.h>
#include <math.h>

#define T_TOK 4096
#define DIM   1024
#define NEXP  8
#define DHID  4096
#define NDOUT 1024
#define BM    128
#define MAXTILES 40   // sum ceil(c_e/128) <= 32+7

typedef short bf16x8 __attribute__((ext_vector_type(8)));
typedef float f32x4 __attribute__((ext_vector_type(4)));

__device__ __forceinline__ unsigned short f2bf(float f) {
  unsigned u = __float_as_uint(f);
  u += 0x7fffu + ((u >> 16) & 1u);        // RNE
  return (unsigned short)(u >> 16);
}
__device__ __forceinline__ unsigned pack2bf(float a, float b) {
  return (unsigned)f2bf(a) | ((unsigned)f2bf(b) << 16);
}
__device__ __forceinline__ void gl_lds16(const void* g, void* l) {
  __builtin_amdgcn_global_load_lds(
      (const __attribute__((address_space(1))) void*)g,
      (__attribute__((address_space(3))) void*)l, 16, 0, 0);
}
// fast GELU (tanh form, v_exp_f32 based). |err| vs exact erf-gelu ~5e-4.
__device__ __forceinline__ float gelu_fast(float h) {
  float z  = 0.79788456080286536f * (h + 0.044715f * h * h * h);
  float az = fabsf(z);
  float et = __expf(-2.0f * az);
  float th = (1.0f - et) / (1.0f + et);
  th = copysignf(th, z);
  return 0.5f * h * (1.0f + th);
}

// -------- gate + x->bf16 conversion fused (1 wave/token, fp64 accum) --------
__global__ __launch_bounds__(256)
void gate_kernel(const float* __restrict__ x, const float* __restrict__ Wg,
                 const float* __restrict__ bg, int* __restrict__ sel,
                 unsigned short* __restrict__ xbf) {
  int lane = threadIdx.x & 63;
  int wid  = threadIdx.x >> 6;
  int t = blockIdx.x * 4 + wid;
  if (t >= T_TOK) return;
  const float* xr = x + (size_t)t * DIM;
  unsigned short* xbr = xbf + (size_t)t * DIM;
  double acc[NEXP];
#pragma unroll
  for (int e = 0; e < NEXP; e++) acc[e] = 0.0;
#pragma unroll
  for (int j = 0; j < 4; j++) {
    int d0 = j * 256 + lane * 4;
    float4 v = *(const float4*)(xr + d0);
    uint2 p; p.x = pack2bf(v.x, v.y); p.y = pack2bf(v.z, v.w);
    *(uint2*)(xbr + d0) = p;
    float xs[4] = {v.x, v.y, v.z, v.w};
#pragma unroll
    for (int i = 0; i < 4; i++) {
      const float4* wr = reinterpret_cast<const float4*>(Wg + (size_t)(d0 + i) * NEXP);
      float4 w0 = wr[0], w1 = wr[1];
      double xv = (double)xs[i];
      acc[0] += xv * (double)w0.x;
      acc[1] += xv * (double)w0.y;
      acc[2] += xv * (double)w0.z;
      acc[3] += xv * (double)w0.w;
      acc[4] += xv * (double)w1.x;
      acc[5] += xv * (double)w1.y;
      acc[6] += xv * (double)w1.z;
      acc[7] += xv * (double)w1.w;
    }
  }
#pragma unroll
  for (int off = 32; off >= 1; off >>= 1) {
#pragma unroll
    for (int e = 0; e < NEXP; e++) acc[e] += __shfl_down(acc[e], off);
  }
  if (lane == 0) {
    double best = acc[0] + (double)bg[0];
    int bi = 0;
#pragma unroll
    for (int e = 1; e < NEXP; e++) {
      double v = acc[e] + (double)bg[e];
      if (v > best) { best = v; bi = e; }   // strict > : first max wins
    }
    sel[t] = bi;
  }
}

// ---------------- routing bookkeeping ----------------
__global__ void zero_kernel(int* __restrict__ counts) {
  if (threadIdx.x < NEXP) counts[threadIdx.x] = 0;
}

__global__ void hist_kernel(const int* __restrict__ sel, int* __restrict__ counts) {
  __shared__ int lc[NEXP];
  if (threadIdx.x < NEXP) lc[threadIdx.x] = 0;
  __syncthreads();
  int t = blockIdx.x * 256 + threadIdx.x;
  atomicAdd(&lc[sel[t]], 1);
  __syncthreads();
  if (threadIdx.x < NEXP) atomicAdd(&counts[threadIdx.x], lc[threadIdx.x]);
}

__global__ void plan_kernel(const int* __restrict__ counts, int* __restrict__ base,
                            int* __restrict__ cursor, int* __restrict__ tileExpert,
                            int* __restrict__ tilePos, int* __restrict__ tileRows,
                            int* __restrict__ ntiles) {
  if (threadIdx.x == 0) {
    int acc = 0, nt = 0;
    for (int e = 0; e < NEXP; e++) {
      base[e] = acc; cursor[e] = acc;
      int c = counts[e];
      for (int j = 0; j < c; j += BM) {
        tileExpert[nt] = e;
        tilePos[nt]    = acc + j;
        int rem = c - j;
        tileRows[nt]   = rem < BM ? rem : BM;
        nt++;
      }
      acc += c;
    }
    *ntiles = nt;
  }
}

__global__ void scatter_kernel(const int* __restrict__ sel, int* __restrict__ cursor,
                               int* __restrict__ list) {
  __shared__ int lcnt[NEXP];
  __shared__ int lbase[NEXP];
  int tid = threadIdx.x;
  if (tid < NEXP) lcnt[tid] = 0;
  __syncthreads();
  int t = blockIdx.x * 256 + tid;
  int e = sel[t];
  int lpos = atomicAdd(&lcnt[e], 1);
  __syncthreads();
  if (tid < NEXP) lbase[tid] = atomicAdd(&cursor[tid], lcnt[tid]);
  __syncthreads();
  list[lbase[e] + lpos] = t;
}

// [E][K][N] fp32 -> tiled swizzled bf16: [E][N/128][K/64] 16KB tiles whose byte
// order equals the GEMM's LDS image: tile[r*128 + (2k ^ ((r&7)<<4))] = elem(n=r, k)
__global__ __launch_bounds__(256)
void transpose_tile_kernel(const float* __restrict__ in, unsigned short* __restrict__ out,
                           int K, int N) {
  int nb = blockIdx.x, kb = blockIdx.y, e = blockIdx.z;
  const float* inp = in + (size_t)e * K * N;
  __shared__ unsigned short lds[128][72];
  int tx = threadIdx.x;
  int kloc = tx >> 5;            // 0..7
  int n4   = (tx & 31) << 2;     // 0..124
#pragma unroll
  for (int p = 0; p < 8; p++) {
    int k = p * 8 + kloc;
    float4 v = *(const float4*)(inp + (size_t)(kb * 64 + k) * N + nb * 128 + n4);
    lds[n4 + 0][k] = f2bf(v.x);
    lds[n4 + 1][k] = f2bf(v.y);
    lds[n4 + 2][k] = f2bf(v.z);
    lds[n4 + 3][k] = f2bf(v.w);
  }
  __syncthreads();
  char* tile = (char*)(out + (((size_t)e * gridDim.x + nb) * gridDim.y + kb) * 8192);
  int r  = tx >> 1;
  int kc0 = (tx & 1) * 32;
#pragma unroll
  for (int c = 0; c < 4; c++) {
    int kc = kc0 + c * 8;
    uint4 v = *(const uint4*)&lds[r][kc];
    *(uint4*)(tile + r * 128 + ((2 * kc) ^ ((r & 7) << 4))) = v;
  }
}

// ============ m97-style single-buffered 128x128 grouped GEMMs ============
// 256 thr = 4 waves (2x2), per-wave 64x64, 32 KiB LDS -> 5 blocks/CU.
// B (and gemm2 A) from tiled swizzled images (gl_lds16 1KB contiguous);
// gemm1 A = token-gathered xbf with pre-swizzled per-lane source.

__global__ __launch_bounds__(256)
void gemm1_kernel(const unsigned short* __restrict__ xbf, const unsigned short* __restrict__ W1T,
                  const float* __restrict__ b1, const int* __restrict__ list,
                  const int* __restrict__ tileExpert, const int* __restrict__ tilePos,
                  const int* __restrict__ tileRows, const int* __restrict__ ntiles,
                  unsigned short* __restrict__ HcT) {
  int tIdx = blockIdx.y;
  if (tIdx >= *ntiles) return;
  int e = tileExpert[tIdx], posBase = tilePos[tIdx], rows = tileRows[tIdx];
  int nb = blockIdx.x;

  __shared__ __align__(1024) char SH[32768];
  char* As = SH;
  char* Bs = SH + 16384;

  const int tx = threadIdx.x, lane = tx & 63, w = tx >> 6;
  const int wm = w >> 1, wn = w & 1;
  const int rsub = lane >> 3;
  const int px = ((lane & 7) ^ rsub) << 4;   // pre-swizzled source for row-major A

  const char* aS[4];
#pragma unroll
  for (int j = 0; j < 4; j++) {
    int r = w * 32 + j * 8 + rsub;
    int tok = list[posBase + (r < rows ? r : rows - 1)];
    aS[j] = (const char*)xbf + (size_t)tok * (DIM * 2) + px;
  }
  const char* bTile = (const char*)W1T + (((size_t)e * (DHID / 128) + nb) * (DIM / 64)) * 16384
                      + w * 4096 + lane * 16;

  f32x4 acc[4][4];
#pragma unroll
  for (int mf = 0; mf < 4; mf++)
#pragma unroll
    for (int nf = 0; nf < 4; nf++)
      acc[mf][nf] = f32x4{0.f, 0.f, 0.f, 0.f};

  const int NT = DIM / 64;   // 16
  for (int kt = 0; kt < NT; kt++) {
#pragma unroll
    for (int j = 0; j < 4; j++) {
      gl_lds16(aS[j] + kt * 128, As + (w * 32 + j * 8) * 128);
      gl_lds16(bTile + kt * 16384 + j * 1024, Bs + w * 4096 + j * 1024);
    }
    __syncthreads();   // drains vmcnt -> staged data visible
#pragma unroll
    for (int ks = 0; ks < 2; ks++) {
      int koff = (ks * 64 + (lane >> 4) * 16) ^ ((lane & 7) << 4);
      bf16x8 aF[4], bF[4];
#pragma unroll
      for (int mf = 0; mf < 4; mf++)
        aF[mf] = *(const bf16x8*)(As + (wm * 64 + mf * 16 + (lane & 15)) * 128 + koff);
#pragma unroll
      for (int nf = 0; nf < 4; nf++)
        bF[nf] = *(const bf16x8*)(Bs + (wn * 64 + nf * 16 + (lane & 15)) * 128 + koff);
#pragma unroll
      for (int mf = 0; mf < 4; mf++)
#pragma unroll
        for (int nf = 0; nf < 4; nf++)
          acc[mf][nf] = __builtin_amdgcn_mfma_f32_16x16x32_bf16(aF[mf], bF[nf], acc[mf][nf], 0, 0, 0);
    }
    __syncthreads();   // readers done before next overwrite
  }

  // ---- Epilogue: bias + fast gelu -> LDS image (exact HcT tile bytes) ->
  //      coalesced 16B copies out. Write all 128 rows (clamped rows harmless).
  const float* b1e = b1 + (size_t)e * DHID;
  const int r4 = (lane >> 4) << 2;
  int xj[4];
#pragma unroll
  for (int j = 0; j < 4; j++) xj[j] = ((r4 + j) & 7) << 4;
#pragma unroll
  for (int nf = 0; nf < 4; nf++) {
    int colLoc = wn * 64 + nf * 16 + (lane & 15);       // 0..127
    int tLoc   = colLoc >> 6;                           // 0/1
    int k2     = (colLoc & 63) * 2;
    float bias = b1e[nb * 128 + colLoc];
    char* base = SH + tLoc * 16384;
#pragma unroll
    for (int mf = 0; mf < 4; mf++) {
      int rBase = wm * 64 + mf * 16 + r4;
#pragma unroll
      for (int j = 0; j < 4; j++) {
        float g = gelu_fast(acc[mf][nf][j] + bias);
        *(unsigned short*)(base + (rBase + j) * 128 + (k2 ^ xj[j])) = f2bf(g);
      }
    }
  }
  __syncthreads();
  const char* src = SH + tx * 128;
  char* dst = (char*)HcT + (size_t)tIdx * (DHID / 64) * 16384
            + (size_t)(nb * 2 + (tx >> 7)) * 16384 + (tx & 127) * 128;
#pragma unroll
  for (int i = 0; i < 8; i++)
    *(uint4*)(dst + i * 16) = *(const uint4*)(src + i * 16);
}

// GEMM2 split-K=2 (z in {0,1}, 32 K-tiles each): fp32 partials, bias in z=0.
__global__ __launch_bounds__(256)
void gemm2_kernel(const unsigned short* __restrict__ HcT, const unsigned short* __restrict__ W2T,
                  const float* __restrict__ b2, const int* __restrict__ tileExpert,
                  const int* __restrict__ tilePos, const int* __restrict__ tileRows,
                  const int* __restrict__ ntiles, float* __restrict__ Ppart) {
  int tIdx = blockIdx.y;
  if (tIdx >= *ntiles) return;
  int e = tileExpert[tIdx], posBase = tilePos[tIdx], rows = tileRows[tIdx];
  int nb = blockIdx.x;
  int zs = blockIdx.z;

  __shared__ __align__(1024) char SH[32768];
  char* As = SH;
  char* Bs = SH + 16384;

  const int tx = threadIdx.x, lane = tx & 63, w = tx >> 6;
  const int wm = w >> 1, wn = w & 1;

  const char* aTile = (const char*)HcT + (size_t)tIdx * (DHID / 64) * 16384
                      + (size_t)zs * 32 * 16384 + w * 4096 + lane * 16;
  const char* bTile = (const char*)W2T + (((size_t)e * (NDOUT / 128) + nb) * (DHID / 64)) * 16384
                      + (size_t)zs * 32 * 16384 + w * 4096 + lane * 16;

  f32x4 acc[4][4];
#pragma unroll
  for (int mf = 0; mf < 4; mf++)
#pragma unroll
    for (int nf = 0; nf < 4; nf++)
      acc[mf][nf] = f32x4{0.f, 0.f, 0.f, 0.f};

  const int NT = 32;
  for (int kt = 0; kt < NT; kt++) {
#pragma unroll
    for (int j = 0; j < 4; j++) {
      gl_lds16(aTile + kt * 16384 + j * 1024, As + w * 4096 + j * 1024);
      gl_lds16(bTile + kt * 16384 + j * 1024, Bs + w * 4096 + j * 1024);
    }
    __syncthreads();
#pragma unroll
    for (int ks = 0; ks < 2; ks++) {
      int koff = (ks * 64 + (lane >> 4) * 16) ^ ((lane & 7) << 4);
      bf16x8 aF[4], bF[4];
#pragma unroll
      for (int mf = 0; mf < 4; mf++)
        aF[mf] = *(const bf16x8*)(As + (wm * 64 + mf * 16 + (lane & 15)) * 128 + koff);
#pragma unroll
      for (int nf = 0; nf < 4; nf++)
        bF[nf] = *(const bf16x8*)(Bs + (wn * 64 + nf * 16 + (lane & 15)) * 128 + koff);
#pragma unroll
      for (int mf = 0; mf < 4; mf++)
#pragma unroll
        for (int nf = 0; nf < 4; nf++)
          acc[mf][nf] = __builtin_amdgcn_mfma_f32_16x16x32_bf16(aF[mf], bF[nf], acc[mf][nf], 0, 0, 0);
    }
    __syncthreads();
  }

  const float* b2e = b2 + (size_t)e * NDOUT;
  float* P = Ppart + (size_t)zs * T_TOK * NDOUT;
#pragma unroll
  for (int nf = 0; nf < 4; nf++) {
    int col = nb * 128 + wn * 64 + nf * 16 + (lane & 15);
    float bias = (zs == 0) ? b2e[col] : 0.f;
#pragma unroll
    for (int mf = 0; mf < 4; mf++)
#pragma unroll
      for (int j = 0; j < 4; j++) {
        int rloc = wm * 64 + mf * 16 + ((lane >> 4) << 2) + j;
        if (rloc < rows)
          P[(size_t)(posBase + rloc) * NDOUT + col] = acc[mf][nf][j] + bias;
      }
  }
}

// out[list[pos]] = P0[pos] + P1[pos]   (bias already in P0)
__global__ __launch_bounds__(256)
void reduce_kernel(const float* __restrict__ Ppart, const int* __restrict__ list,
                   float* __restrict__ out) {
  int pos = blockIdx.x;
  int tok = list[pos];
  int c = threadIdx.x * 4;
  float4 a = *(const float4*)(Ppart + (size_t)pos * NDOUT + c);
  float4 b = *(const float4*)(Ppart + (size_t)T_TOK * NDOUT + (size_t)pos * NDOUT + c);
  float4 o; o.x = a.x + b.x; o.y = a.y + b.y; o.z = a.z + b.z; o.w = a.w + b.w;
  *(float4*)(out + (size_t)tok * NDOUT + c) = o;
}

// ---------------- launch ----------------
extern "C" void kernel_launch(void* const* d_in, const int* in_sizes, int n_in,
                              void* d_out, int out_size, void* d_ws, size_t ws_size,
                              hipStream_t stream) {
  const float* x  = (const float*)d_in[0];
  const float* Wg = (const float*)d_in[1];
  const float* bg = (const float*)d_in[2];
  const float* W1 = (const float*)d_in[3];
  const float* b1 = (const float*)d_in[4];
  const float* W2 = (const float*)d_in[5];
  const float* b2 = (const float*)d_in[6];
  float* out = (float*)d_out;

  char* ws = (char*)d_ws;
  int* sel        = (int*)(ws);
  int* counts     = (int*)(ws + 16384);
  int* base       = (int*)(ws + 16448);
  int* cursor     = (int*)(ws + 16512);
  int* ntiles     = (int*)(ws + 16576);
  int* tileExpert = (int*)(ws + 16640);
  int* tilePos    = (int*)(ws + 16832);
  int* tileRows   = (int*)(ws + 17024);
  int* list       = (int*)(ws + 17408);

  unsigned short* xbf = (unsigned short*)(ws + (1ull << 20));    // 8 MB
  unsigned short* HcT = (unsigned short*)(ws + (10ull << 20));   // 40 MB tiled Hc
  unsigned short* W1T = (unsigned short*)(ws + (52ull << 20));   // 64 MB tiled
  unsigned short* W2T = (unsigned short*)(ws + (116ull << 20));  // 64 MB tiled
  float* Ppart        = (float*)(ws + (52ull << 20));            // reuse W1T region (2x16.8 MB)

  gate_kernel<<<T_TOK / 4, 256, 0, stream>>>(x, Wg, bg, sel, xbf);
  zero_kernel<<<1, 64, 0, stream>>>(counts);
  hist_kernel<<<T_TOK / 256, 256, 0, stream>>>(sel, counts);
  plan_kernel<<<1, 64, 0, stream>>>(counts, base, cursor, tileExpert, tilePos, tileRows, ntiles);
  scatter_kernel<<<T_TOK / 256, 256, 0, stream>>>(sel, cursor, list);

  transpose_tile_kernel<<<dim3(DHID / 128, DIM / 64, NEXP), 256, 0, stream>>>(W1, W1T, DIM, DHID);
  transpose_tile_kernel<<<dim3(NDOUT / 128, DHID / 64, NEXP), 256, 0, stream>>>(W2, W2T, DHID, NDOUT);

  gemm1_kernel<<<dim3(DHID / 128, MAXTILES), 256, 0, stream>>>(
      xbf, W1T, b1, list, tileExpert, tilePos, tileRows, ntiles, HcT);
  gemm2_kernel<<<dim3(NDOUT / 128, MAXTILES, 2), 256, 0, stream>>>(
      HcT, W2T, b2, tileExpert, tilePos, tileRows, ntiles, Ppart);
  reduce_kernel<<<T_TOK, 256, 0, stream>>>(Ppart, list, out);
}